// Round 2
// baseline (807.267 us; speedup 1.0000x reference)
//
#include <hip/hip_runtime.h>

#define S_LEN 2048
#define NL 51
#define LS 53
#define ST 51
#define EN 52
#define NBATCH 256
#define L2E 1.4426950408889634f
#define LN2 0.6931471805599453f

typedef unsigned int u32x2 __attribute__((ext_vector_type(2)));

__device__ __forceinline__ float rlane(float v, int l) {
    return __builtin_bit_cast(float, __builtin_amdgcn_readlane(__builtin_bit_cast(int, v), l));
}

// v_mov_b32 with DPP lane permute (pure VALU, 2 cyc, VGPR->VGPR)
#define DPP(SRC, CTRL) __builtin_amdgcn_update_dpp(0, (SRC), (CTRL), 0xF, 0xF, false)
// DPP ctrl encodings: quad_perm[1,0,3,2]=177 (l^1), [2,3,0,1]=78 (l^2),
// [3,2,1,0]=27 (l^3), ROW_MIRROR=0x140 (l^15 in row16), ROW_HALF_MIRROR=0x141 (l^7)

// One block per batch element, 2 waves.
// Wave 0: forward recursion, multiplicative domain, lagged divisor (math
// identical to R2..R6, all passed):
//   e_{t+1} = s_t * q_t,  s_t = E e_t,  q_t = gexp_t * rcp(ssum_{t-1}),
//   ssum = s[START]; applied divisors' log2 -> off2.
// R8: XOR ALL-GATHER BROADCAST. R6 showed 53 v_readlane ~6.5cyc each
// (SGPR-writeback throughput); R7 showed LDS RTT is worse on a 1-wave
// serial chain. Now: build 64 broadcast regs in 63 pure-VALU cross-lane
// ops (1 permlane32_swap + 2 permlane16_swap + 60 DPP movs), all XOR lane
// maps: reg(b,X)[l] = e[((l^X)&15)+b], b in {0,16,32,48}, X in 0..15.
// E is preloaded PER-LANE PERMUTED to match: P(b,X) = exp(T[j][c]-tmax),
// c = ((j^X)&15)+b (0 if c>=53). Matvec = 64 all-VGPR FMAs. No SGPR
// ports on the hot path except 1 readlane/step (ssum).
// Wave 1: gold score (latency-tolerant global gathers), unchanged.
__global__ __launch_bounds__(128, 1) void crf_kernel(
    const float* __restrict__ logits,   // [256, 2048, 51]
    const int*   __restrict__ labels,   // [256, 2048]
    const int*   __restrict__ lens,     // [256]
    const float* __restrict__ Tr,       // [53, 53]  (to, from)
    float*       __restrict__ out)      // [256]
{
    const int b   = blockIdx.x;
    const int tid = threadIdx.x;
    const int len = lens[b];
    __shared__ float sh_gold;
    __shared__ float sh_norm;

    if (tid >= 64) {
        // ---- wave 1: gold score ----
        const int lid = tid - 64;
        const int* lb = labels + (long)b * S_LEN;
        const float* lg = logits + (long)b * S_LEN * NL;
        float p = 0.f;
        for (int t = lid; t < len; t += 64) {
            const int lab  = lb[t];
            const int prev = (t == 0) ? ST : lb[t - 1];
            p += lg[(long)t * NL + lab] + Tr[lab * LS + prev];
        }
        if (lid == 0) p += Tr[EN * LS + lb[len - 1]];   // final transition to END
#pragma unroll
        for (int off = 32; off > 0; off >>= 1)
            p += __shfl_down(p, off, 64);
        if (lid == 0) sh_gold = p;
    } else {
        // ---- wave 0: forward scan ----
        const int j  = tid;
        const int jj = (j < NL) ? j : 0;     // safe column for inactive lanes
        const float* trow = Tr + j * LS;

#define FOR16(M,B) M(B,0) M(B,1) M(B,2) M(B,3) M(B,4) M(B,5) M(B,6) M(B,7) \
                   M(B,8) M(B,9) M(B,10) M(B,11) M(B,12) M(B,13) M(B,14) M(B,15)
#define FORALL(M)  FOR16(M,0) FOR16(M,1) FOR16(M,2) FOR16(M,3)

        // P(b,X) = er value for column c = ((j^X)&15) + 16*B  (XOR-permuted E row)
#define DECLP(B,X) float p##B##_##X;
        FORALL(DECLP)
#define LOADP(B,X) { const int c = ((j ^ X) & 15) + 16*B; \
                     p##B##_##X = ((j < LS) && (c < LS)) ? trow[c] : -1e30f; }
        FORALL(LOADP)
        float tmax = -1e30f;
#define MAXP(B,X) tmax = fmaxf(tmax, p##B##_##X);
        FORALL(MAXP)
        // exp(T - tmax); invalid entries -> 0 (or 1 on lanes j>=53 where
        // tmax=-1e30, harmless: their q stays 0 so e stays 0, same as R6).
#define EXPP(B,X) p##B##_##X = __builtin_amdgcn_exp2f((p##B##_##X - tmax) * L2E);
        FORALL(EXPP)

        const float* lg = logits + (long)b * S_LEN * NL;

        float buf[4];
        buf[0] = lg[0 * NL + jj];
        buf[1] = lg[1 * NL + jj];
        buf[2] = lg[2 * NL + jj];
        buf[3] = lg[3 * NL + jj];          // rows 0..3 always in-bounds (len>=1)

        float e     = (j == ST) ? 1.f : 0.f;   // exp(alpha0)
        float off2  = 0.f;                     // sum of log2 of APPLIED divisors
        float lprev = 0.f;                     // log2 of divisor inside current q
        float nl0   = (j < NL) ? buf[0] : -100.f;
        float q     = __builtin_amdgcn_exp2f((nl0 + tmax) * L2E);   // gexp_0

        // ---- 63-op XOR all-gather: r{B}_{X}[l] = e[((l^X)&15) + 16*B] ----
#define BQ(B) \
        const int r##B##_1 = DPP(r##B##_0, 177); \
        const int r##B##_2 = DPP(r##B##_0, 78);  \
        const int r##B##_3 = DPP(r##B##_0, 27);
#define BH(B) \
        const int r##B##_7 = DPP(r##B##_0, 0x141); \
        const int r##B##_6 = DPP(r##B##_1, 0x141); \
        const int r##B##_5 = DPP(r##B##_2, 0x141); \
        const int r##B##_4 = DPP(r##B##_3, 0x141);
#define BMIR(B) \
        const int r##B##_15 = DPP(r##B##_0, 0x140); \
        const int r##B##_14 = DPP(r##B##_1, 0x140); \
        const int r##B##_13 = DPP(r##B##_2, 0x140); \
        const int r##B##_12 = DPP(r##B##_3, 0x140); \
        const int r##B##_11 = DPP(r##B##_4, 0x140); \
        const int r##B##_10 = DPP(r##B##_5, 0x140); \
        const int r##B##_9  = DPP(r##B##_6, 0x140); \
        const int r##B##_8  = DPP(r##B##_7, 0x140);
#define BCAST \
        const int e_i = __builtin_bit_cast(int, e); \
        const u32x2 sw32 = __builtin_amdgcn_permlane32_swap((unsigned)e_i, (unsigned)e_i, false, false); \
        const u32x2 swA  = __builtin_amdgcn_permlane16_swap(sw32[0], sw32[0], false, false); \
        const u32x2 swB  = __builtin_amdgcn_permlane16_swap(sw32[1], sw32[1], false, false); \
        const int r0_0 = (int)swA[0]; const int r1_0 = (int)swA[1]; \
        const int r2_0 = (int)swB[0]; const int r3_0 = (int)swB[1]; \
        BQ(0) BQ(1) BQ(2) BQ(3) \
        BH(0) BH(1) BH(2) BH(3) \
        BMIR(0) BMIR(1) BMIR(2) BMIR(3)

#define RF(B,X) __builtin_bit_cast(float, r##B##_##X)
#define F_L(B,X) aL##B = fmaf(RF(B,X), p##B##_##X, aL##B);
#define F_H(B,X) aH##B = fmaf(RF(B,X), p##B##_##X, aH##B);
#define FOR8L(M,B) M(B,0) M(B,1) M(B,2) M(B,3) M(B,4) M(B,5) M(B,6) M(B,7)
#define FOR8H(M,B) M(B,8) M(B,9) M(B,10) M(B,11) M(B,12) M(B,13) M(B,14) M(B,15)
#define MATVEC(SOUT) { \
        float aL0=0.f,aH0=0.f,aL1=0.f,aH1=0.f,aL2=0.f,aH2=0.f,aL3=0.f,aH3=0.f; \
        FOR8L(F_L,0) FOR8H(F_H,0) FOR8L(F_L,1) FOR8H(F_H,1) \
        FOR8L(F_L,2) FOR8H(F_H,2) FOR8L(F_L,3) FOR8H(F_H,3) \
        SOUT = ((aL0+aH0)+(aL1+aH1)) + ((aL2+aH2)+(aL3+aH3)); }

#define STEP(NLRAW) { \
        const float nl = (j < NL) ? (NLRAW) : -100.f; \
        BCAST \
        float sv; MATVEC(sv) \
        e = sv * q; \
        const float ssum = rlane(sv, ST); \
        off2 += lprev; \
        lprev = __builtin_amdgcn_logf(ssum); \
        q = __builtin_amdgcn_exp2f((nl + tmax) * L2E) * __builtin_amdgcn_rcpf(ssum); }

        int t = 0;
#pragma unroll 1
        while (t + 4 <= len) {
            {   // i = 0  (t+4 <= len <= 2047: in-bounds, no clamp)
                float pf = lg[(long)(t + 4) * NL + jj];
                STEP(buf[1])
                buf[0] = pf;
            }
            {   // i = 1
                int ti = t + 5; ti = (ti < S_LEN) ? ti : (S_LEN - 1);
                float pf = lg[(long)ti * NL + jj];
                STEP(buf[2])
                buf[1] = pf;
            }
            {   // i = 2
                int ti = t + 6; ti = (ti < S_LEN) ? ti : (S_LEN - 1);
                float pf = lg[(long)ti * NL + jj];
                STEP(buf[3])
                buf[2] = pf;
            }
            {   // i = 3
                int ti = t + 7; ti = (ti < S_LEN) ? ti : (S_LEN - 1);
                float pf = lg[(long)ti * NL + jj];
                STEP(buf[0])
                buf[3] = pf;
            }
            t += 4;
        }
        // tail: <= 3 steps; slot m holds row t+m; "next" logit of the last
        // step is in-bounds (row <= len <= 2047) and its q is never applied.
#pragma unroll
        for (int i = 0; i < 4; ++i) {
            if (t + i < len) {
                STEP(buf[(i + 1) & 3])
            }
        }

        // norm = logsumexp_j(alpha[j] + T[END, j]) : one more matvec, row END
        float sEnd;
        {
            BCAST
            float sv; MATVEC(sv)
            sEnd = rlane(sv, EN);
        }
        const float tmEnd = rlane(tmax, EN);
        if (j == 0)
            sh_norm = (off2 + __builtin_amdgcn_logf(sEnd)) * LN2 + tmEnd;
    }
    __syncthreads();
    if (tid == 0) out[b] = sh_gold - sh_norm;
}

extern "C" void kernel_launch(void* const* d_in, const int* in_sizes, int n_in,
                              void* d_out, int out_size, void* d_ws, size_t ws_size,
                              hipStream_t stream) {
    const float* logits = (const float*)d_in[0];
    const int*   labels = (const int*)d_in[1];
    const int*   lens   = (const int*)d_in[2];
    const float* Tr     = (const float*)d_in[3];
    float*       out    = (float*)d_out;
    crf_kernel<<<NBATCH, 128, 0, stream>>>(logits, labels, lens, Tr, out);
}

// Round 3
// 678.440 us; speedup vs baseline: 1.1899x; 1.1899x over previous
//
#include <hip/hip_runtime.h>

#define S_LEN 2048
#define NL 51
#define LS 53
#define ST 51
#define EN 52
#define NBATCH 256
#define L2E 1.4426950408889634f
#define LN2 0.6931471805599453f

typedef float f32x4 __attribute__((ext_vector_type(4)));

__device__ __forceinline__ float rlane(float v, int l) {
    return __builtin_bit_cast(float, __builtin_amdgcn_readlane(__builtin_bit_cast(int, v), l));
}
__device__ __forceinline__ float bperm(int idx, float v) {
    return __builtin_bit_cast(float, __builtin_amdgcn_ds_bpermute(idx, __builtin_bit_cast(int, v)));
}

// One block per batch element, 2 waves.
// Wave 0: forward recursion, multiplicative domain, lagged divisor (math
// IDENTICAL to R6, the 405us baseline):
//   e_{t+1} = s_t * q_t,  s_t = E e_t,  q_t = gexp_t * rcp(ssum_{t-1}),
//   ssum = s[START]; applied divisors' log2 -> off2.
// R9: HYBRID GATHER — split the 53-value broadcast across TWO pipes that
// run concurrently: cols 0..25 via v_readlane (VALU port, SGPR dests),
// cols 26..52 via ds_bpermute (DS pipe, register crossbar, no LDS memory,
// latency on lgkmcnt). Index VGPRs for bpermute are precomputed outside
// the loop (no per-step v_movs). Gathers are issued at the END of each
// step (right after e = s*q) so the DS flight hides under the q-chain and
// the next matvec's readlane-fed FMAs. bpermutes split 14/13 around the
// readlane block to stay within the 15-deep lgkmcnt window.
// Col 52 kept: T[START,END]=100 (row START written after col-END -100),
// so lane ST's sum includes e[END] — dropping it changes the answer.
// Wave 1: gold score (latency-tolerant global gathers), unchanged.
__global__ __launch_bounds__(128, 1) void crf_kernel(
    const float* __restrict__ logits,   // [256, 2048, 51]
    const int*   __restrict__ labels,   // [256, 2048]
    const int*   __restrict__ lens,     // [256]
    const float* __restrict__ Tr,       // [53, 53]  (to, from)
    float*       __restrict__ out)      // [256]
{
    const int b   = blockIdx.x;
    const int tid = threadIdx.x;
    const int len = lens[b];
    __shared__ float sh_gold;
    __shared__ float sh_norm;

    if (tid >= 64) {
        // ---- wave 1: gold score ----
        const int lid = tid - 64;
        const int* lb = labels + (long)b * S_LEN;
        const float* lg = logits + (long)b * S_LEN * NL;
        float p = 0.f;
        for (int t = lid; t < len; t += 64) {
            const int lab  = lb[t];
            const int prev = (t == 0) ? ST : lb[t - 1];
            p += lg[(long)t * NL + lab] + Tr[lab * LS + prev];
        }
        if (lid == 0) p += Tr[EN * LS + lb[len - 1]];   // final transition to END
#pragma unroll
        for (int off = 32; off > 0; off >>= 1)
            p += __shfl_down(p, off, 64);
        if (lid == 0) sh_gold = p;
    } else {
        // ---- wave 0: forward scan ----
        const int j  = tid;
        const int jj = (j < NL) ? j : 0;     // safe column for inactive lanes
        const float* trow = Tr + j * LS;

        f32x4 er0, er1, er2, er3, er4, er5, er6, er7, er8, er9, er10, er11, er12;
        float er13x;
#define GT(K)    (((j < LS) && ((K) < LS)) ? trow[(K)] : -1e30f)
#define LD4(V,B) { V.x = GT(B); V.y = GT((B)+1); V.z = GT((B)+2); V.w = GT((B)+3); }
        LD4(er0, 0)  LD4(er1, 4)  LD4(er2, 8)   LD4(er3, 12)
        LD4(er4, 16) LD4(er5, 20) LD4(er6, 24)  LD4(er7, 28)
        LD4(er8, 32) LD4(er9, 36) LD4(er10, 40) LD4(er11, 44)
        LD4(er12, 48)
        er13x = GT(52);
#undef GT
#undef LD4
        float tmax = fmaxf(-1e30f, er13x);
#define MX4(V) tmax = fmaxf(tmax, fmaxf(fmaxf(V.x, V.y), fmaxf(V.z, V.w)));
        MX4(er0) MX4(er1) MX4(er2) MX4(er3) MX4(er4) MX4(er5) MX4(er6)
        MX4(er7) MX4(er8) MX4(er9) MX4(er10) MX4(er11) MX4(er12)
#undef MX4
        // er = exp(T - tmax). Lanes j>=53: tmax=-1e30 -> er=1, but their q
        // stays 0 (nl=-100, tmax=-1e30) so e stays 0 and they contribute 0.
#define EX4(V) { V.x = __builtin_amdgcn_exp2f((V.x - tmax) * L2E); \
                 V.y = __builtin_amdgcn_exp2f((V.y - tmax) * L2E); \
                 V.z = __builtin_amdgcn_exp2f((V.z - tmax) * L2E); \
                 V.w = __builtin_amdgcn_exp2f((V.w - tmax) * L2E); }
        EX4(er0) EX4(er1) EX4(er2) EX4(er3) EX4(er4) EX4(er5) EX4(er6)
        EX4(er7) EX4(er8) EX4(er9) EX4(er10) EX4(er11) EX4(er12)
#undef EX4
        er13x = __builtin_amdgcn_exp2f((er13x - tmax) * L2E);

        const float* lg = logits + (long)b * S_LEN * NL;

        float buf[4];
        buf[0] = lg[0 * NL + jj];
        buf[1] = lg[1 * NL + jj];
        buf[2] = lg[2 * NL + jj];
        buf[3] = lg[3 * NL + jj];          // rows 0..3 always in-bounds (len>=1)

        float e     = (j == ST) ? 1.f : 0.f;   // exp(alpha0)
        float off2  = 0.f;                     // sum of log2 of APPLIED divisors
        float lprev = 0.f;                     // log2 of divisor inside current q
        float nl0   = (j < NL) ? buf[0] : -100.f;
        float q     = __builtin_amdgcn_exp2f((nl0 + tmax) * L2E);   // gexp_0

        // precomputed bpermute byte-indices (VGPRs, live across the loop)
#define IXDECL(K) int ix##K = (K) * 4;
        IXDECL(26) IXDECL(27) IXDECL(28) IXDECL(29) IXDECL(30) IXDECL(31)
        IXDECL(32) IXDECL(33) IXDECL(34) IXDECL(35) IXDECL(36) IXDECL(37)
        IXDECL(38) IXDECL(39) IXDECL(40) IXDECL(41) IXDECL(42) IXDECL(43)
        IXDECL(44) IXDECL(45) IXDECL(46) IXDECL(47) IXDECL(48) IXDECL(49)
        IXDECL(50) IXDECL(51) IXDECL(52)
#undef IXDECL

        // gather destinations
        float b0,b1,b2,b3,b4,b5,b6,b7,b8,b9,b10,b11,b12,b13,b14,b15,b16,b17,
              b18,b19,b20,b21,b22,b23,b24,b25;
        float g26,g27,g28,g29,g30,g31,g32,g33,g34,g35,g36,g37,g38,g39,g40,
              g41,g42,g43,g44,g45,g46,g47,g48,g49,g50,g51,g52;

        // GATHER(EV): 14 bpermutes, 26 readlanes (DS flight drains under
        // them), 13 more bpermutes, then pin everything before the barrier.
#define GATHER(EV) { \
            g26 = bperm(ix26, EV); g27 = bperm(ix27, EV); g28 = bperm(ix28, EV); \
            g29 = bperm(ix29, EV); g30 = bperm(ix30, EV); g31 = bperm(ix31, EV); \
            g32 = bperm(ix32, EV); g33 = bperm(ix33, EV); g34 = bperm(ix34, EV); \
            g35 = bperm(ix35, EV); g36 = bperm(ix36, EV); g37 = bperm(ix37, EV); \
            g38 = bperm(ix38, EV); g39 = bperm(ix39, EV); \
            b0  = rlane(EV, 0);  b1  = rlane(EV, 1);  b2  = rlane(EV, 2); \
            b3  = rlane(EV, 3);  b4  = rlane(EV, 4);  b5  = rlane(EV, 5); \
            b6  = rlane(EV, 6);  b7  = rlane(EV, 7);  b8  = rlane(EV, 8); \
            b9  = rlane(EV, 9);  b10 = rlane(EV, 10); b11 = rlane(EV, 11); \
            b12 = rlane(EV, 12); b13 = rlane(EV, 13); b14 = rlane(EV, 14); \
            b15 = rlane(EV, 15); b16 = rlane(EV, 16); b17 = rlane(EV, 17); \
            b18 = rlane(EV, 18); b19 = rlane(EV, 19); b20 = rlane(EV, 20); \
            b21 = rlane(EV, 21); b22 = rlane(EV, 22); b23 = rlane(EV, 23); \
            b24 = rlane(EV, 24); b25 = rlane(EV, 25); \
            g40 = bperm(ix40, EV); g41 = bperm(ix41, EV); g42 = bperm(ix42, EV); \
            g43 = bperm(ix43, EV); g44 = bperm(ix44, EV); g45 = bperm(ix45, EV); \
            g46 = bperm(ix46, EV); g47 = bperm(ix47, EV); g48 = bperm(ix48, EV); \
            g49 = bperm(ix49, EV); g50 = bperm(ix50, EV); g51 = bperm(ix51, EV); \
            g52 = bperm(ix52, EV); \
            __builtin_amdgcn_sched_barrier(0); }

        // matvec: readlane-fed columns first (SGPRs ready earliest), then
        // bpermute-fed in DS return order.
#define MATVEC(SOUT) { \
            float ax = 0.f, ay = 0.f, az = 0.f, aw = 0.f; \
            ax = fmaf(b0,  er0.x, ax); ay = fmaf(b1,  er0.y, ay); \
            az = fmaf(b2,  er0.z, az); aw = fmaf(b3,  er0.w, aw); \
            ax = fmaf(b4,  er1.x, ax); ay = fmaf(b5,  er1.y, ay); \
            az = fmaf(b6,  er1.z, az); aw = fmaf(b7,  er1.w, aw); \
            ax = fmaf(b8,  er2.x, ax); ay = fmaf(b9,  er2.y, ay); \
            az = fmaf(b10, er2.z, az); aw = fmaf(b11, er2.w, aw); \
            ax = fmaf(b12, er3.x, ax); ay = fmaf(b13, er3.y, ay); \
            az = fmaf(b14, er3.z, az); aw = fmaf(b15, er3.w, aw); \
            ax = fmaf(b16, er4.x, ax); ay = fmaf(b17, er4.y, ay); \
            az = fmaf(b18, er4.z, az); aw = fmaf(b19, er4.w, aw); \
            ax = fmaf(b20, er5.x, ax); ay = fmaf(b21, er5.y, ay); \
            az = fmaf(b22, er5.z, az); aw = fmaf(b23, er5.w, aw); \
            ax = fmaf(b24, er6.x, ax); ay = fmaf(b25, er6.y, ay); \
            az = fmaf(g26, er6.z, az); aw = fmaf(g27, er6.w, aw); \
            ax = fmaf(g28, er7.x, ax); ay = fmaf(g29, er7.y, ay); \
            az = fmaf(g30, er7.z, az); aw = fmaf(g31, er7.w, aw); \
            ax = fmaf(g32, er8.x, ax); ay = fmaf(g33, er8.y, ay); \
            az = fmaf(g34, er8.z, az); aw = fmaf(g35, er8.w, aw); \
            ax = fmaf(g36, er9.x, ax); ay = fmaf(g37, er9.y, ay); \
            az = fmaf(g38, er9.z, az); aw = fmaf(g39, er9.w, aw); \
            ax = fmaf(g40, er10.x, ax); ay = fmaf(g41, er10.y, ay); \
            az = fmaf(g42, er10.z, az); aw = fmaf(g43, er10.w, aw); \
            ax = fmaf(g44, er11.x, ax); ay = fmaf(g45, er11.y, ay); \
            az = fmaf(g46, er11.z, az); aw = fmaf(g47, er11.w, aw); \
            ax = fmaf(g48, er12.x, ax); ay = fmaf(g49, er12.y, ay); \
            az = fmaf(g50, er12.z, az); aw = fmaf(g51, er12.w, aw); \
            ax = fmaf(g52, er13x, ax); \
            SOUT = (ax + ay) + (az + aw); }

        // prologue gather of e0
        GATHER(e)

#define STEP(NLRAW) { \
            float nl = (j < NL) ? (NLRAW) : -100.f; \
            float sv; MATVEC(sv); \
            e = sv * q; \
            GATHER(e) \
            float ssum = rlane(sv, ST); \
            off2 += lprev; \
            lprev = __builtin_amdgcn_logf(ssum); \
            q = __builtin_amdgcn_exp2f((nl + tmax) * L2E) * __builtin_amdgcn_rcpf(ssum); }

        int t = 0;
#pragma unroll 1
        while (t + 4 <= len) {
            {   // i = 0  (t+4 <= len <= 2047: in-bounds, no clamp)
                float pf = lg[(long)(t + 4) * NL + jj];
                STEP(buf[1])
                buf[0] = pf;
            }
            {   // i = 1
                int ti = t + 5; ti = (ti < S_LEN) ? ti : (S_LEN - 1);
                float pf = lg[(long)ti * NL + jj];
                STEP(buf[2])
                buf[1] = pf;
            }
            {   // i = 2
                int ti = t + 6; ti = (ti < S_LEN) ? ti : (S_LEN - 1);
                float pf = lg[(long)ti * NL + jj];
                STEP(buf[3])
                buf[2] = pf;
            }
            {   // i = 3
                int ti = t + 7; ti = (ti < S_LEN) ? ti : (S_LEN - 1);
                float pf = lg[(long)ti * NL + jj];
                STEP(buf[0])
                buf[3] = pf;
            }
            t += 4;
        }
        // tail: <= 3 steps; slot m holds row t+m; "next" logit of the last
        // step is in-bounds (row <= len <= 2047) and its q is never applied.
#pragma unroll
        for (int i = 0; i < 4; ++i) {
            if (t + i < len) {
                STEP(buf[(i + 1) & 3])
            }
        }

        // norm = logsumexp_j(alpha[j] + T[END, j]) : one more matvec, row END.
        // Gathers of the final e were issued by the last STEP.
        float sv; MATVEC(sv);
        float sEnd  = rlane(sv, EN);
        float tmEnd = rlane(tmax, EN);
        if (j == 0)
            sh_norm = (off2 + __builtin_amdgcn_logf(sEnd)) * LN2 + tmEnd;
#undef STEP
#undef MATVEC
#undef GATHER
    }
    __syncthreads();
    if (tid == 0) out[b] = sh_gold - sh_norm;
}

extern "C" void kernel_launch(void* const* d_in, const int* in_sizes, int n_in,
                              void* d_out, int out_size, void* d_ws, size_t ws_size,
                              hipStream_t stream) {
    const float* logits = (const float*)d_in[0];
    const int*   labels = (const int*)d_in[1];
    const int*   lens   = (const int*)d_in[2];
    const float* Tr     = (const float*)d_in[3];
    float*       out    = (float*)d_out;
    crf_kernel<<<NBATCH, 128, 0, stream>>>(logits, labels, lens, Tr, out);
}

// Round 4
// 505.762 us; speedup vs baseline: 1.5961x; 1.3414x over previous
//
#include <hip/hip_runtime.h>

#define S_LEN 2048
#define NL 51
#define LS 53
#define ST 51
#define EN 52
#define NBATCH 256
#define L2E 1.4426950408889634f
#define LN2 0.6931471805599453f

#define CHUNK 64
#define CH_BYTES (CHUNK * NL * 4)          // 13056 B per chunk window start stride
#define BUF_FLOATS 3328                    // 13*256 floats = 13312 B (covers 65 rows = 13260 B)
#define BATCH_BYTES (S_LEN * NL * 4)       // 417792

typedef float f32x4 __attribute__((ext_vector_type(4)));

__device__ __forceinline__ float rlane(float v, int l) {
    return __builtin_bit_cast(float, __builtin_amdgcn_readlane(__builtin_bit_cast(int, v), l));
}

// One block per batch element, 2 waves, WAVE-SPECIALIZED:
//   wave0 = consumer: forward recursion (math IDENTICAL to R6, the verified
//           405us baseline: 53 batched readlanes + sched_barrier + 54 FMAs,
//           multiplicative domain, lagged divisor).
//   wave1 = producer: stages 65-row logit windows into double-buffered LDS
//           via global_load_lds (13 x 16B issues), ONE FULL CHUNK (~15K cyc)
//           ahead of consumption; also computes the gold score (its original
//           job) chunk-interleaved.
// R10 theory: R6's ~245 cyc/step stall was the vmcnt drain on the global
// logit prefetch (1-step lookahead vs ~500-900 cyc HBM stream latency).
// Staging converts that into a ds_read_b32 issued at step top and consumed
// at step bottom (~200 cyc gap >> ~120 cyc LDS latency -> hidden).
// Window c covers rows [c*64, c*64+64] (65 rows, 16B-aligned start);
// step r consumes row r+1 = window-local (r - c*64 + 1) in [1,64].
// Per-lane source clamp to BATCH_BYTES-16 makes the final window safe;
// clamped garbage lands in LDS floats >= 3264, consumed max is 3263.
__global__ __launch_bounds__(128, 1) void crf_kernel(
    const float* __restrict__ logits,   // [256, 2048, 51]
    const int*   __restrict__ labels,   // [256, 2048]
    const int*   __restrict__ lens,     // [256]
    const float* __restrict__ Tr,       // [53, 53]  (to, from)
    float*       __restrict__ out)      // [256]
{
    const int b   = blockIdx.x;
    const int tid = threadIdx.x;
    const int len = lens[b];
    const int nch = (len + CHUNK - 1) / CHUNK;

    __shared__ float sh_gold;
    __shared__ float sh_norm;
    __shared__ float sh_log[2][BUF_FLOATS];

    const float* lg  = logits + (long)b * S_LEN * NL;
    const char*  lgb = (const char*)lg;

    // ---- wave0 persistent scan state (dead registers on wave1) ----
    const int j  = tid;                  // lane (wave0)
    const int jj = (j < NL) ? j : 0;     // safe column for inactive lanes
    f32x4 er0, er1, er2, er3, er4, er5, er6, er7, er8, er9, er10, er11, er12, er13;
    float tmax = -1e30f;
    float e = 0.f, q = 0.f, off2 = 0.f, lprev = 0.f;

    // staging helper: issue 13 x 16B global_load_lds for window cc into buffer bs
#define STAGE(CC, BS) { \
        const int base = (CC) * CH_BYTES + (tid - 64) * 16; \
        _Pragma("unroll") \
        for (int i = 0; i < 13; ++i) { \
            int off = base + i * 1024; \
            off = (off > BATCH_BYTES - 16) ? (BATCH_BYTES - 16) : off; \
            __builtin_amdgcn_global_load_lds((const void*)(lgb + off), \
                                             (void*)&sh_log[BS][i * 256], 16, 0, 0); \
        } }

    if (tid >= 64) {
        // ---- wave1 prologue: stage window 0 ----
        STAGE(0, 0)
    } else {
        // ---- wave0 prologue: load transition row, tmax, exp (global Tr) ----
        const float* trow = Tr + j * LS;
#define GT(K)    (((j < LS) && ((K) < LS)) ? trow[(K)] : -1e30f)
#define LD4(V,B) { V.x = GT(B); V.y = GT((B)+1); V.z = GT((B)+2); V.w = GT((B)+3); }
        LD4(er0, 0)  LD4(er1, 4)  LD4(er2, 8)   LD4(er3, 12)
        LD4(er4, 16) LD4(er5, 20) LD4(er6, 24)  LD4(er7, 28)
        LD4(er8, 32) LD4(er9, 36) LD4(er10, 40) LD4(er11, 44)
        LD4(er12, 48) LD4(er13, 52)
#undef GT
#undef LD4
#define MX4(V) tmax = fmaxf(tmax, fmaxf(fmaxf(V.x, V.y), fmaxf(V.z, V.w)));
        MX4(er0) MX4(er1) MX4(er2) MX4(er3) MX4(er4) MX4(er5) MX4(er6)
        MX4(er7) MX4(er8) MX4(er9) MX4(er10) MX4(er11) MX4(er12) MX4(er13)
#undef MX4
        // er = exp(T - tmax). Lanes j>=53: tmax=-1e30 -> er=1, but their q
        // stays 0 (nl=-100, tmax=-1e30) so e stays 0 and they contribute 0.
#define EX4(V) { V.x = __builtin_amdgcn_exp2f((V.x - tmax) * L2E); \
                 V.y = __builtin_amdgcn_exp2f((V.y - tmax) * L2E); \
                 V.z = __builtin_amdgcn_exp2f((V.z - tmax) * L2E); \
                 V.w = __builtin_amdgcn_exp2f((V.w - tmax) * L2E); }
        EX4(er0) EX4(er1) EX4(er2) EX4(er3) EX4(er4) EX4(er5) EX4(er6)
        EX4(er7) EX4(er8) EX4(er9) EX4(er10) EX4(er11) EX4(er12) EX4(er13)
#undef EX4
        e = (j == ST) ? 1.f : 0.f;       // exp(alpha0)
    }

    __syncthreads();                      // window 0 staged

    if (tid < 64) {
        // q init from LDS row 0 (window 0 local 0)
        const float v   = sh_log[0][jj];
        const float nl0 = (j < NL) ? v : -100.f;
        q = __builtin_amdgcn_exp2f((nl0 + tmax) * L2E);   // gexp_0
    }

    // ---- scan macros (MATVEC/STEP identical math to R6) ----
#define RL4(G) float b##G##0 = rlane(e, 4*G), b##G##1 = rlane(e, 4*G+1), \
                     b##G##2 = rlane(e, 4*G+2), b##G##3 = rlane(e, 4*G+3);
#define FM4(G, EV) { ax = fmaf(b##G##0, EV.x, ax); ay = fmaf(b##G##1, EV.y, ay); \
                     az = fmaf(b##G##2, EV.z, az); aw = fmaf(b##G##3, EV.w, aw); }
#define MATVEC(SOUT) { \
            RL4(0) RL4(1) RL4(2) RL4(3) RL4(4) RL4(5) RL4(6) \
            RL4(7) RL4(8) RL4(9) RL4(10) RL4(11) RL4(12) \
            float b130 = rlane(e, 52); \
            __builtin_amdgcn_sched_barrier(0); \
            float ax = 0.f, ay = 0.f, az = 0.f, aw = 0.f; \
            FM4(0, er0) FM4(1, er1) FM4(2, er2) FM4(3, er3) FM4(4, er4) \
            FM4(5, er5) FM4(6, er6) FM4(7, er7) FM4(8, er8) FM4(9, er9) \
            FM4(10, er10) FM4(11, er11) FM4(12, er12) \
            ax = fmaf(b130, er13.x, ax); \
            SOUT = (ax + ay) + (az + aw); }

    // nl select AFTER the matvec so the lgkmcnt wait for NLV sinks to the use
#define STEP(NLV) { \
            float sv; MATVEC(sv); \
            e = sv * q; \
            float ssum = rlane(sv, ST); \
            off2 += lprev; \
            lprev = __builtin_amdgcn_logf(ssum); \
            float nl = (j < NL) ? (NLV) : -100.f; \
            q = __builtin_amdgcn_exp2f((nl + tmax) * L2E) * __builtin_amdgcn_rcpf(ssum); }

    float p = 0.f;                        // wave1 gold accumulator

    for (int c = 0; c < nch; ++c) {
        if (tid >= 64) {
            // ---- producer: stage next window, gold partial for chunk c ----
            if (c + 1 < nch) STAGE(c + 1, (c + 1) & 1)
            const int lid = tid - 64;
            const int r = c * CHUNK + lid;
            if (r < len) {
                const int* lb = labels + (long)b * S_LEN;
                const int lab  = lb[r];
                const int prev = (r == 0) ? ST : lb[r - 1];
                p += lg[(long)r * NL + lab] + Tr[lab * LS + prev];
            }
        } else {
            // ---- consumer: steps r in [c*64, min((c+1)*64, len)) ----
            const float* Ljj = sh_log[c & 1] + jj;
            const int kend = (len - c * CHUNK < CHUNK) ? (len - c * CHUNK) : CHUNK;
            int k = 0;
#pragma unroll 1
            while (k + 4 <= kend) {
                const float* Lr = Ljj + (k + 1) * NL;
                float n0 = Lr[0];
                float n1 = Lr[NL];
                float n2 = Lr[2 * NL];
                float n3 = Lr[3 * NL];
                STEP(n0)
                STEP(n1)
                STEP(n2)
                STEP(n3)
                k += 4;
            }
#pragma unroll 1
            while (k < kend) {
                float n0 = Ljj[(k + 1) * NL];
                STEP(n0)
                ++k;
            }
        }
        __syncthreads();   // window c consumed; window c+1 staged & visible
    }

    if (tid >= 64) {
        // ---- finalize gold ----
        const int lid = tid - 64;
        const int* lb = labels + (long)b * S_LEN;
        if (lid == 0) p += Tr[EN * LS + lb[len - 1]];   // final transition to END
#pragma unroll
        for (int off = 32; off > 0; off >>= 1)
            p += __shfl_down(p, off, 64);
        if (lid == 0) sh_gold = p;
    } else {
        // ---- norm = logsumexp_j(alpha[j] + T[END, j]) : one more matvec ----
        float sv; MATVEC(sv);
        const float sEnd  = rlane(sv, EN);
        const float tmEnd = rlane(tmax, EN);
        if (j == 0)
            sh_norm = (off2 + __builtin_amdgcn_logf(sEnd)) * LN2 + tmEnd;
    }
#undef STEP
#undef MATVEC
#undef RL4
#undef FM4
#undef STAGE

    __syncthreads();
    if (tid == 0) out[b] = sh_gold - sh_norm;
}

extern "C" void kernel_launch(void* const* d_in, const int* in_sizes, int n_in,
                              void* d_out, int out_size, void* d_ws, size_t ws_size,
                              hipStream_t stream) {
    const float* logits = (const float*)d_in[0];
    const int*   labels = (const int*)d_in[1];
    const int*   lens   = (const int*)d_in[2];
    const float* Tr     = (const float*)d_in[3];
    float*       out    = (float*)d_out;
    crf_kernel<<<NBATCH, 128, 0, stream>>>(logits, labels, lens, Tr, out);
}

// Round 5
// 356.773 us; speedup vs baseline: 2.2627x; 1.4176x over previous
//
#include <hip/hip_runtime.h>

#define S_LEN 2048
#define NL 51
#define LS 53
#define ST 51
#define EN 52
#define NBATCH 256
#define L2E 1.4426950408889634f
#define LN2 0.6931471805599453f

typedef float f32x4 __attribute__((ext_vector_type(4)));

__device__ __forceinline__ float rlane(float v, int l) {
    return __builtin_bit_cast(float, __builtin_amdgcn_readlane(__builtin_bit_cast(int, v), l));
}

// R11: SPLIT THE SERIAL CHAIN. norm = f . M_{len-1} ... M_0 . a0 (LSE semiring)
// is factored at m = ceil(len/2):
//   wave0: forward alpha-scan, steps 0..m-1       (R6-verified STEP, row-major E)
//   wave1: backward beta-scan, steps len-1..m     (same STEP, column-major E)
//   wave2: gold score (unchanged)
// combine: norm = LN2*(off2_f + off2_b + log2(dot(e_fwd, e_bwd))).
// Backward specifics:
//  - logit applies to the SOURCE side -> folded into q (symmetric to forward).
//  - divisor = rlane(s',53): lane 53's er row is all-ones (garbage-lane trick),
//    so s'[53] = sum of the gather input — the analog of forward's row-START.
//  - DENORMAL FIX: T rows ST/EN carry +100 which would force e^{-100} scaling
//    (below f32 normal -> FTZ -> zeros). Shift: T'[j,k] = T[j,k]-100 for
//    j in {ST,EN}, and backward mask value 0 (g'_ST = g'_EN = 1). Exact.
// Per-step cost is unchanged (~451 cyc, structural dep-latency of 1 wave);
// serial depth halves: 2047 -> ~1024 steps.
__global__ __launch_bounds__(192, 1) void crf_kernel(
    const float* __restrict__ logits,   // [256, 2048, 51]
    const int*   __restrict__ labels,   // [256, 2048]
    const int*   __restrict__ lens,     // [256]
    const float* __restrict__ Tr,       // [53, 53]  (to, from)
    float*       __restrict__ out)      // [256]
{
    const int b   = blockIdx.x;
    const int tid = threadIdx.x;
    const int len = lens[b];
    const int bsteps = len >> 1;          // floor(len/2)
    const int fsteps = len - bsteps;      // ceil(len/2) >= 1

    __shared__ float sh_gold;
    __shared__ float sh_eb[64];
    __shared__ float sh_off2b;

    const float* lg = logits + (long)b * S_LEN * NL;

    float eF = 0.f, off2F = 0.f;          // forward results (read after barrier)

    // ---- shared scan macros (STEP math identical to verified R6) ----
#define RL4(G) float b##G##0 = rlane(e, 4*G), b##G##1 = rlane(e, 4*G+1), \
                     b##G##2 = rlane(e, 4*G+2), b##G##3 = rlane(e, 4*G+3);
#define FM4(G, EV) { ax = fmaf(b##G##0, EV.x, ax); ay = fmaf(b##G##1, EV.y, ay); \
                     az = fmaf(b##G##2, EV.z, az); aw = fmaf(b##G##3, EV.w, aw); }
#define MATVEC(SOUT) { \
            RL4(0) RL4(1) RL4(2) RL4(3) RL4(4) RL4(5) RL4(6) \
            RL4(7) RL4(8) RL4(9) RL4(10) RL4(11) RL4(12) \
            float b130 = rlane(e, 52); \
            __builtin_amdgcn_sched_barrier(0); \
            float ax = 0.f, ay = 0.f, az = 0.f, aw = 0.f; \
            FM4(0, er0) FM4(1, er1) FM4(2, er2) FM4(3, er3) FM4(4, er4) \
            FM4(5, er5) FM4(6, er6) FM4(7, er7) FM4(8, er8) FM4(9, er9) \
            FM4(10, er10) FM4(11, er11) FM4(12, er12) \
            ax = fmaf(b130, er13.x, ax); \
            SOUT = (ax + ay) + (az + aw); }
    // DL = divisor lane; MV = mask value for inactive-logit lanes
#define STEP(NLV, DL, MV) { \
            float sv; MATVEC(sv); \
            e = sv * q; \
            float ssum = rlane(sv, DL); \
            off2 += lprev; \
            lprev = __builtin_amdgcn_logf(ssum); \
            float nl = (lane < NL) ? (NLV) : (MV); \
            q = __builtin_amdgcn_exp2f((nl + tmax) * L2E) * __builtin_amdgcn_rcpf(ssum); }

    if (tid >= 128) {
        // ---- wave2: gold score ----
        const int lid = tid - 128;
        const int* lb = labels + (long)b * S_LEN;
        float p = 0.f;
        for (int t = lid; t < len; t += 64) {
            const int lab  = lb[t];
            const int prev = (t == 0) ? ST : lb[t - 1];
            p += lg[(long)t * NL + lab] + Tr[lab * LS + prev];
        }
        if (lid == 0) p += Tr[EN * LS + lb[len - 1]];   // final transition to END
#pragma unroll
        for (int off = 32; off > 0; off >>= 1)
            p += __shfl_down(p, off, 64);
        if (lid == 0) sh_gold = p;
    } else if (tid >= 64) {
        // ---- wave1: backward beta-scan (column-major, shifted T') ----
        const int lane = tid - 64;
        const int jj = (lane < NL) ? lane : 0;

        f32x4 er0, er1, er2, er3, er4, er5, er6, er7, er8, er9, er10, er11, er12, er13;
#define GTB(K) (((lane < LS) && ((K) < LS)) ? \
                (Tr[(K) * LS + lane] - ((((K)==ST)||((K)==EN)) ? 100.f : 0.f)) : -1e30f)
#define LD4B(V,B) { V.x = GTB(B); V.y = GTB((B)+1); V.z = GTB((B)+2); V.w = GTB((B)+3); }
        LD4B(er0, 0)  LD4B(er1, 4)  LD4B(er2, 8)   LD4B(er3, 12)
        LD4B(er4, 16) LD4B(er5, 20) LD4B(er6, 24)  LD4B(er7, 28)
        LD4B(er8, 32) LD4B(er9, 36) LD4B(er10, 40) LD4B(er11, 44)
        LD4B(er12, 48) LD4B(er13, 52)
#undef GTB
#undef LD4B
        float tmax = -1e30f;
#define MX4(V) tmax = fmaxf(tmax, fmaxf(fmaxf(V.x, V.y), fmaxf(V.z, V.w)));
        MX4(er0) MX4(er1) MX4(er2) MX4(er3) MX4(er4) MX4(er5) MX4(er6)
        MX4(er7) MX4(er8) MX4(er9) MX4(er10) MX4(er11) MX4(er12) MX4(er13)
#undef MX4
        // er = exp(T' - tmax). Lane 53: all entries -1e30 -> er == 1 (all-ones
        // row) -> s'[53] = sum of gather input = the rescale divisor.
#define EX4(V) { V.x = __builtin_amdgcn_exp2f((V.x - tmax) * L2E); \
                 V.y = __builtin_amdgcn_exp2f((V.y - tmax) * L2E); \
                 V.z = __builtin_amdgcn_exp2f((V.z - tmax) * L2E); \
                 V.w = __builtin_amdgcn_exp2f((V.w - tmax) * L2E); }
        EX4(er0) EX4(er1) EX4(er2) EX4(er3) EX4(er4) EX4(er5) EX4(er6)
        EX4(er7) EX4(er8) EX4(er9) EX4(er10) EX4(er11) EX4(er12) EX4(er13)
#undef EX4

        // init: b_len[k] = T[EN,k]; mult domain with global shift 100:
        // e = exp(T[EN,k] - 100), off2 = 100*L2E. Lanes >= 53 -> e = 0.
        float rawEN = (lane < LS) ? (Tr[EN * LS + lane] - 100.f) : -1e30f;
        float e     = __builtin_amdgcn_exp2f(rawEN * L2E);
        float off2  = 100.f * L2E;
        float lprev = 0.f;
        // q for the first step restores tmax only (first logit pre-folded into
        // e below); q = 0 on lanes >= 53 keeps garbage lanes at zero.
        float q     = __builtin_amdgcn_exp2f(tmax * L2E);

        float buf[4] = {0.f, 0.f, 0.f, 0.f};
        if (bsteps >= 1) {
            // fold g_{len-1} (source-side logit, mask value 0) into e
            float nlL = (lane < NL) ? lg[(long)(len - 1) * NL + jj] : 0.f;
            e *= __builtin_amdgcn_exp2f(nlL * L2E);
            // prefetch rows len-2-m (consumed descending)
            int r;
            buf[0] = lg[(long)(len - 2) * NL + jj];            // bsteps>=1 -> len>=2
            r = len - 3; r = r < 0 ? 0 : r; buf[1] = lg[(long)r * NL + jj];
            r = len - 4; r = r < 0 ? 0 : r; buf[2] = lg[(long)r * NL + jj];
            r = len - 5; r = r < 0 ? 0 : r; buf[3] = lg[(long)r * NL + jj];
        }

        int i = 0;
#pragma unroll 1
        while (i + 4 <= bsteps) {
            { int pr = len - 6 - i; pr = pr < 0 ? 0 : pr;
              float pf = lg[(long)pr * NL + jj]; STEP(buf[0], 53, 0.f) buf[0] = pf; }
            { int pr = len - 7 - i; pr = pr < 0 ? 0 : pr;
              float pf = lg[(long)pr * NL + jj]; STEP(buf[1], 53, 0.f) buf[1] = pf; }
            { int pr = len - 8 - i; pr = pr < 0 ? 0 : pr;
              float pf = lg[(long)pr * NL + jj]; STEP(buf[2], 53, 0.f) buf[2] = pf; }
            { int pr = len - 9 - i; pr = pr < 0 ? 0 : pr;
              float pf = lg[(long)pr * NL + jj]; STEP(buf[3], 53, 0.f) buf[3] = pf; }
            i += 4;
        }
#pragma unroll
        for (int m = 0; m < 4; ++m) {
            if (i + m < bsteps) { STEP(buf[m], 53, 0.f) }
        }

        sh_eb[lane] = e;
        if (lane == 0) sh_off2b = off2;
    } else {
        // ---- wave0: forward alpha-scan (R6 verbatim, bound fsteps) ----
        const int lane = tid;
        const int jj = (lane < NL) ? lane : 0;
        const float* trow = Tr + lane * LS;

        f32x4 er0, er1, er2, er3, er4, er5, er6, er7, er8, er9, er10, er11, er12, er13;
#define GT(K)    (((lane < LS) && ((K) < LS)) ? trow[(K)] : -1e30f)
#define LD4(V,B) { V.x = GT(B); V.y = GT((B)+1); V.z = GT((B)+2); V.w = GT((B)+3); }
        LD4(er0, 0)  LD4(er1, 4)  LD4(er2, 8)   LD4(er3, 12)
        LD4(er4, 16) LD4(er5, 20) LD4(er6, 24)  LD4(er7, 28)
        LD4(er8, 32) LD4(er9, 36) LD4(er10, 40) LD4(er11, 44)
        LD4(er12, 48) LD4(er13, 52)
#undef GT
#undef LD4
        float tmax = -1e30f;
#define MX4(V) tmax = fmaxf(tmax, fmaxf(fmaxf(V.x, V.y), fmaxf(V.z, V.w)));
        MX4(er0) MX4(er1) MX4(er2) MX4(er3) MX4(er4) MX4(er5) MX4(er6)
        MX4(er7) MX4(er8) MX4(er9) MX4(er10) MX4(er11) MX4(er12) MX4(er13)
#undef MX4
#define EX4(V) { V.x = __builtin_amdgcn_exp2f((V.x - tmax) * L2E); \
                 V.y = __builtin_amdgcn_exp2f((V.y - tmax) * L2E); \
                 V.z = __builtin_amdgcn_exp2f((V.z - tmax) * L2E); \
                 V.w = __builtin_amdgcn_exp2f((V.w - tmax) * L2E); }
        EX4(er0) EX4(er1) EX4(er2) EX4(er3) EX4(er4) EX4(er5) EX4(er6)
        EX4(er7) EX4(er8) EX4(er9) EX4(er10) EX4(er11) EX4(er12) EX4(er13)
#undef EX4

        float buf[4];
        buf[0] = lg[0 * NL + jj];
        buf[1] = lg[1 * NL + jj];
        buf[2] = lg[2 * NL + jj];
        buf[3] = lg[3 * NL + jj];          // rows 0..3 in-bounds (len>=1)

        float e     = (lane == ST) ? 1.f : 0.f;   // exp(alpha0)
        float off2  = 0.f;
        float lprev = 0.f;
        float nl0   = (lane < NL) ? buf[0] : -100.f;
        float q     = __builtin_amdgcn_exp2f((nl0 + tmax) * L2E);   // gexp_0

        int t = 0;
#pragma unroll 1
        while (t + 4 <= fsteps) {
            {   // i = 0  (t+4 <= fsteps <= 2047: in-bounds, no clamp)
                float pf = lg[(long)(t + 4) * NL + jj];
                STEP(buf[1], ST, -100.f)
                buf[0] = pf;
            }
            {   // i = 1
                int ti = t + 5; ti = (ti < S_LEN) ? ti : (S_LEN - 1);
                float pf = lg[(long)ti * NL + jj];
                STEP(buf[2], ST, -100.f)
                buf[1] = pf;
            }
            {   // i = 2
                int ti = t + 6; ti = (ti < S_LEN) ? ti : (S_LEN - 1);
                float pf = lg[(long)ti * NL + jj];
                STEP(buf[3], ST, -100.f)
                buf[2] = pf;
            }
            {   // i = 3
                int ti = t + 7; ti = (ti < S_LEN) ? ti : (S_LEN - 1);
                float pf = lg[(long)ti * NL + jj];
                STEP(buf[0], ST, -100.f)
                buf[3] = pf;
            }
            t += 4;
        }
        // tail: slot m holds row t+m; consumed row t+i+1 = slot (i+1)&3;
        // i==3 never executes (loop exit => fsteps - t <= 3).
#pragma unroll
        for (int i = 0; i < 4; ++i) {
            if (t + i < fsteps) {
                STEP(buf[(i + 1) & 3], ST, -100.f)
            }
        }

        eF    = e;
        off2F = off2;
    }
#undef STEP
#undef MATVEC
#undef RL4
#undef FM4

    __syncthreads();

    if (tid < 64) {
        // combine: norm = LN2*(off2_f + off2_b + log2(dot(e_fwd, e_bwd)))
        float d = eF * sh_eb[tid];
#pragma unroll
        for (int off = 32; off > 0; off >>= 1)
            d += __shfl_xor(d, off, 64);
        if (tid == 0) {
            float norm = LN2 * (off2F + sh_off2b + __builtin_amdgcn_logf(d));
            out[b] = sh_gold - norm;
        }
    }
}

extern "C" void kernel_launch(void* const* d_in, const int* in_sizes, int n_in,
                              void* d_out, int out_size, void* d_ws, size_t ws_size,
                              hipStream_t stream) {
    const float* logits = (const float*)d_in[0];
    const int*   labels = (const int*)d_in[1];
    const int*   lens   = (const int*)d_in[2];
    const float* Tr     = (const float*)d_in[3];
    float*       out    = (float*)d_out;
    crf_kernel<<<NBATCH, 192, 0, stream>>>(logits, labels, lens, Tr, out);
}